// Round 11
// baseline (59.055 us; speedup 1.0000x reference)
//
#include <hip/hip_runtime.h>
#include <hip/hip_bf16.h>
#include <math.h>
#include <stdint.h>

#define NS 8192       // samples
#define DD 1024       // feature dim
#define NP 512        // prototypes
#define MT 128        // M rows per block
#define NT 64         // N cols per block
#define KQ 256        // K quarter
#define NPARTS 8      // one per N-block
#define EPSF 1e-9f
#define BIGF 3.0e38f

typedef __attribute__((ext_vector_type(8))) short bf16x8;
typedef __attribute__((ext_vector_type(4))) float f32x4;

__device__ inline unsigned short f32_to_bf16(float f) {
    uint32_t u = __builtin_bit_cast(uint32_t, f);
    uint32_t r = (u + 0x7FFFu + ((u >> 16) & 1u)) >> 16;
    return (unsigned short)r;
}

// x and protos f32 -> bf16 + exact f32 row sums of squares (R2-verified).
__global__ __launch_bounds__(256) void prep_kernel(
    const float* __restrict__ x, const float* __restrict__ protos,
    unsigned short* __restrict__ xb, unsigned short* __restrict__ pb,
    float* __restrict__ xsq, float* __restrict__ psq)
{
    int row = blockIdx.x;
    const float* src;
    unsigned short* dstb;
    float* dsts;
    if (row < NS) {
        src = x + (size_t)row * DD; dstb = xb + (size_t)row * DD; dsts = xsq + row;
    } else {
        int r = row - NS;
        src = protos + (size_t)r * DD; dstb = pb + (size_t)r * DD; dsts = psq + r;
    }
    int t = threadIdx.x;
    float4 v = ((const float4*)src)[t];
    float ss = v.x * v.x + v.y * v.y + v.z * v.z + v.w * v.w;
    ushort4 o;
    o.x = f32_to_bf16(v.x); o.y = f32_to_bf16(v.y);
    o.z = f32_to_bf16(v.z); o.w = f32_to_bf16(v.w);
    ((ushort4*)dstb)[t] = o;
    for (int off = 32; off; off >>= 1) ss += __shfl_down(ss, off);
    __shared__ float red[4];
    if ((t & 63) == 0) red[t >> 6] = ss;
    __syncthreads();
    if (t == 0) dsts[0] = red[0] + red[1] + red[2] + red[3];
}

// Barrier-free-inner fused GEMM+min. 128x64 tile, 8 waves (4 row-groups x 2
// col-halves, wave-tile 32x32). K in 4 quarters: B quarter-slice (64x256 bf16
// = 32 KB) staged via global_load_lds into XOR-swizzled dbuf LDS; ONE barrier
// per quarter. Within a quarter each wave free-runs: A bf16 frags loaded
// global->reg (no ds_write), swizzled ds_read B, MFMA -- register deps only.
__global__ __launch_bounds__(512, 2) void glvq_fused(
    const unsigned short* __restrict__ xb, const unsigned short* __restrict__ pb,
    const float* __restrict__ xsq, const float* __restrict__ psq,
    const int* __restrict__ y,
    float* __restrict__ d1p, float* __restrict__ d2p)
{
    __shared__ unsigned short Bs[2][NT * KQ];   // 2 x 32 KB
    __shared__ float dpart[MT][2][2];           // 2 KB

    const int tid  = threadIdx.x;
    const int lane = tid & 63;
    const int wid  = tid >> 6;        // 0..7
    const int wg   = wid >> 1;        // 0..3: rows wg*32..+31
    const int wc   = wid & 1;         // 0..1: cols wc*32..+31
    const int d    = blockIdx.x;      // 0..511
    const int xcd  = d & 7;
    const int slot = d >> 3;          // 0..63
    const int mb   = xcd * 8 + (slot & 7);    // 0..63
    const int nb   = slot >> 3;               // 0..7
    const int m0   = mb * MT;
    const int n0   = nb * NT;
    const int sub  = lane & 15, g = lane >> 4;

    f32x4 acc[2][2] = {};

    // stage quarter q into Bs[buf]: wave w covers rows w*8..w*8+7, 4 insts x 1KB
    // (1 inst = 2 rows of 512B). LDS dest linear; source chunk pre-swizzled
    // with the same involution used on the read side: c ^= (row & 15).
    auto stage = [&](int buf, int q) {
#pragma unroll
        for (int j = 0; j < 4; ++j) {
            const int rbase = wid * 8 + j * 2;
            const int row   = rbase + (lane >> 5);
            const int sc    = (lane & 31) ^ (row & 15);
            const unsigned short* gp = pb + (size_t)(n0 + row) * DD + q * KQ + sc * 8;
            __builtin_amdgcn_global_load_lds(
                (const __attribute__((address_space(1))) void*)gp,
                (__attribute__((address_space(3))) void*)((char*)&Bs[buf][0] + rbase * 512),
                16, 0, 0);
        }
    };

    const unsigned short* xr0 = xb + (size_t)(m0 + wg * 32 + sub) * DD;       // m=0 row
    const unsigned short* xr1 = xr0 + (size_t)16 * DD;                         // m=1 row

    auto computeQ = [&](int buf, int q) {
#pragma unroll
        for (int kt = 0; kt < KQ / 32; ++kt) {   // 8 K-steps of 32
            bf16x8 a0 = *(const bf16x8*)(xr0 + q * KQ + kt * 32 + g * 8);
            bf16x8 a1 = *(const bf16x8*)(xr1 + q * KQ + kt * 32 + g * 8);
            const int c    = kt * 4 + g;
            const int col0 = wc * 32 + sub;
            const int col1 = wc * 32 + 16 + sub;
            bf16x8 b0 = *(const bf16x8*)((const char*)&Bs[buf][0] + col0 * 512 + ((c ^ (col0 & 15)) * 16));
            bf16x8 b1 = *(const bf16x8*)((const char*)&Bs[buf][0] + col1 * 512 + ((c ^ (col1 & 15)) * 16));
            acc[0][0] = __builtin_amdgcn_mfma_f32_16x16x32_bf16(a0, b0, acc[0][0], 0, 0, 0);
            acc[0][1] = __builtin_amdgcn_mfma_f32_16x16x32_bf16(a0, b1, acc[0][1], 0, 0, 0);
            acc[1][0] = __builtin_amdgcn_mfma_f32_16x16x32_bf16(a1, b0, acc[1][0], 0, 0, 0);
            acc[1][1] = __builtin_amdgcn_mfma_f32_16x16x32_bf16(a1, b1, acc[1][1], 0, 0, 0);
        }
    };

    // 4 quarters, dbuf, ONE barrier per quarter. stage(q+1) flies under
    // computeQ(q) (~2500 cy); __syncthreads' vmcnt(0) drain is amortized.
    stage(0, 0);
    __syncthreads();
    stage(1, 1); computeQ(0, 0); __syncthreads();
    stage(0, 2); computeQ(1, 1); __syncthreads();
    stage(1, 3); computeQ(0, 2); __syncthreads();
    computeQ(1, 3);

    // ---- epilogue: masked mins over this wave's 32 cols ----
    float psqv[2];
    int   lab[2];
#pragma unroll
    for (int n = 0; n < 2; ++n) {
        const int col = n0 + wc * 32 + n * 16 + sub;
        psqv[n] = psq[col];
        lab[n]  = col >> 2;   // prototype label = col / PPC
    }
#pragma unroll
    for (int m = 0; m < 2; ++m) {
#pragma unroll
        for (int r = 0; r < 4; ++r) {
            const int rl = wg * 32 + m * 16 + g * 4 + r;
            const float xs = xsq[m0 + rl];
            const int yy = y[m0 + rl];
            float d1 = BIGF, d2 = BIGF;
#pragma unroll
            for (int n = 0; n < 2; ++n) {
                const float dist = xs + psqv[n] - 2.0f * acc[m][n][r];
                if (lab[n] == yy) d1 = fminf(d1, dist);
                else              d2 = fminf(d2, dist);
            }
            for (int off = 8; off; off >>= 1) {
                d1 = fminf(d1, __shfl_xor(d1, off));
                d2 = fminf(d2, __shfl_xor(d2, off));
            }
            if (sub == 0) { dpart[rl][wc][0] = d1; dpart[rl][wc][1] = d2; }
        }
    }
    __syncthreads();
    if (tid < MT) {
        d1p[nb * NS + m0 + tid] = fminf(dpart[tid][0][0], dpart[tid][1][0]);
        d2p[nb * NS + m0 + tid] = fminf(dpart[tid][0][1], dpart[tid][1][1]);
    }
}

__global__ __launch_bounds__(256) void finalize_kernel(
    const float* __restrict__ d1p, const float* __restrict__ d2p,
    const int* __restrict__ tval, float* __restrict__ bsum)
{
    const int row = blockIdx.x * 256 + threadIdx.x;
    float d1 = BIGF, d2 = BIGF;
#pragma unroll
    for (int p = 0; p < NPARTS; ++p) {
        d1 = fminf(d1, d1p[p * NS + row]);
        d2 = fminf(d2, d2p[p * NS + row]);
    }
    const float mu = (d1 - d2) / (d1 + d2 + EPSF);
    const float alpha = logf(1.0f + (float)tval[0]);
    float s = 1.0f / (1.0f + expf(-alpha * mu));
    for (int off = 32; off; off >>= 1) s += __shfl_down(s, off);
    __shared__ float red[4];
    if ((threadIdx.x & 63) == 0) red[threadIdx.x >> 6] = s;
    __syncthreads();
    if (threadIdx.x == 0) bsum[blockIdx.x] = red[0] + red[1] + red[2] + red[3];
}

__global__ void final_sum(const float* __restrict__ bsum, float* __restrict__ out) {
    float s = (threadIdx.x < NS / 256) ? bsum[threadIdx.x] : 0.0f;
    for (int off = 32; off; off >>= 1) s += __shfl_down(s, off);
    if (threadIdx.x == 0) out[0] = s * (1.0f / (float)NS);
}

extern "C" void kernel_launch(void* const* d_in, const int* in_sizes, int n_in,
                              void* d_out, int out_size, void* d_ws, size_t ws_size,
                              hipStream_t stream) {
    const float* x      = (const float*)d_in[0];
    const int*   y      = (const int*)d_in[1];
    const int*   tval   = (const int*)d_in[2];
    const float* protos = (const float*)d_in[3];
    float* out = (float*)d_out;

    char* ws = (char*)d_ws;
    unsigned short* xb = (unsigned short*)(ws);                                // 16 MB
    unsigned short* pb = (unsigned short*)(ws + (size_t)NS * DD * 2);          // 1 MB
    float* xsq  = (float*)(ws + (size_t)(NS + NP) * DD * 2);                   // 32 KB
    float* psq  = (float*)(ws + (size_t)(NS + NP) * DD * 2 + NS * 4);          // 2 KB
    float* d1p  = (float*)(ws + (size_t)(NS + NP) * DD * 2 + (NS + NP) * 4);   // 256 KB
    float* d2p  = d1p + (size_t)NPARTS * NS;                                   // 256 KB
    float* bsum = d2p + (size_t)NPARTS * NS;                                   // 128 B

    prep_kernel<<<NS + NP, 256, 0, stream>>>(x, protos, xb, pb, xsq, psq);
    glvq_fused<<<(NS / MT) * (NP / NT), 512, 0, stream>>>(xb, pb, xsq, psq, y, d1p, d2p);
    finalize_kernel<<<NS / 256, 256, 0, stream>>>(d1p, d2p, tval, bsum);
    final_sum<<<1, 64, 0, stream>>>(bsum, out);
}

// Round 12
// 37.420 us; speedup vs baseline: 1.5782x; 1.5782x over previous
//
#include <hip/hip_runtime.h>
#include <hip/hip_bf16.h>
#include <math.h>
#include <stdint.h>

#define NS 8192       // samples
#define DD 1024       // feature dim
#define NP 512        // prototypes
#define BK 64         // K-chunk
#define MT 64         // M rows per block
#define NT 128        // N cols per block
#define NSTEP (DD / BK)   // 16
#define NPARTS 8      // 4 N-blocks * 2 wave-col-halves
#define EPSF 1e-9f
#define BIGF 3.0e38f

typedef __attribute__((ext_vector_type(8))) short bf16x8;
typedef __attribute__((ext_vector_type(4))) float f32x4;

__device__ inline unsigned short f32_to_bf16(float f) {
    uint32_t u = __builtin_bit_cast(uint32_t, f);
    uint32_t r = (u + 0x7FFFu + ((u >> 16) & 1u)) >> 16;
    return (unsigned short)r;
}

// x and protos f32 -> bf16 + exact f32 row sums of squares (R2-verified).
__global__ __launch_bounds__(256) void prep_kernel(
    const float* __restrict__ x, const float* __restrict__ protos,
    unsigned short* __restrict__ xb, unsigned short* __restrict__ pb,
    float* __restrict__ xsq, float* __restrict__ psq)
{
    int row = blockIdx.x;
    const float* src;
    unsigned short* dstb;
    float* dsts;
    if (row < NS) {
        src = x + (size_t)row * DD; dstb = xb + (size_t)row * DD; dsts = xsq + row;
    } else {
        int r = row - NS;
        src = protos + (size_t)r * DD; dstb = pb + (size_t)r * DD; dsts = psq + r;
    }
    int t = threadIdx.x;
    float4 v = ((const float4*)src)[t];
    float ss = v.x * v.x + v.y * v.y + v.z * v.z + v.w * v.w;
    ushort4 o;
    o.x = f32_to_bf16(v.x); o.y = f32_to_bf16(v.y);
    o.z = f32_to_bf16(v.z); o.w = f32_to_bf16(v.w);
    ((ushort4*)dstb)[t] = o;
    for (int off = 32; off; off >>= 1) ss += __shfl_down(ss, off);
    __shared__ float red[4];
    if ((t & 63) == 0) red[t >> 6] = ss;
    __syncthreads();
    if (t == 0) dsts[0] = red[0] + red[1] + red[2] + red[3];
}

// GEMM+min, tri-buffered counted-vmcnt pipeline. BOTH A and B staged via
// global_load_lds from prep'd bf16 (no VALU staging in loop). Per iter:
// vmcnt(6) [drain tile kt exactly; tile kt+1 stays in flight] -> barrier ->
// stage(kt+2) [buffer freed by compute(kt-1), all readers pre-barrier] ->
// compute(kt). Every stage gets >= 1 full compute phase. 64x128 tile, 4
// waves (2Mx2N, wave 32x64), XOR-swizzled LDS, grid 512, XCD L2-resident
// slices (2MB xb + 1MB pb per XCD).
__global__ __launch_bounds__(256, 2) void glvq_gemm(
    const unsigned short* __restrict__ xb, const unsigned short* __restrict__ pb,
    const float* __restrict__ xsq, const float* __restrict__ psq,
    const int* __restrict__ y,
    float* __restrict__ d1p, float* __restrict__ d2p)
{
    __shared__ unsigned short As[3][MT * BK];   // 3 x 8 KB
    __shared__ unsigned short Bs[3][NT * BK];   // 3 x 16 KB

    const int tid  = threadIdx.x;
    const int lane = tid & 63;
    const int wid  = tid >> 6;        // 0..3
    const int wr = wid >> 1;
    const int wc = wid & 1;
    const int d    = blockIdx.x;      // 0..511
    const int xcd  = d & 7;
    const int slot = d >> 3;          // 0..63
    const int mb   = xcd * 16 + (slot & 15);   // 0..127 (per-XCD 16 M-blocks)
    const int nb   = slot >> 4;                // 0..3
    const int m0   = mb * MT;
    const int n0   = nb * NT;

    const int srow   = lane >> 3;                 // 0..7
    const int scol16 = (lane & 7) ^ srow;         // pre-swizzled source chunk
    const int sub = lane & 15, g = lane >> 4;

    f32x4 acc[2][4] = {};

    // stage tile kt into buf: A 2 gll/thread (8 chunks of 8 rows: c=wid*2+j),
    // B 4 gll/thread (16 chunks: c=wid*4+j). Linear LDS dest, swizzled source.
    auto stage = [&](int buf, int kt) {
        const int k0 = kt * BK;
#pragma unroll
        for (int j = 0; j < 2; ++j) {
            const int c = wid * 2 + j;
            const unsigned short* ga = xb + (size_t)(m0 + c * 8 + srow) * DD + k0 + scol16 * 8;
            __builtin_amdgcn_global_load_lds(
                (const __attribute__((address_space(1))) void*)ga,
                (__attribute__((address_space(3))) void*)((char*)&As[buf][0] + c * 1024),
                16, 0, 0);
        }
#pragma unroll
        for (int j = 0; j < 4; ++j) {
            const int c = wid * 4 + j;
            const unsigned short* gb = pb + (size_t)(n0 + c * 8 + srow) * DD + k0 + scol16 * 8;
            __builtin_amdgcn_global_load_lds(
                (const __attribute__((address_space(1))) void*)gb,
                (__attribute__((address_space(3))) void*)((char*)&Bs[buf][0] + c * 1024),
                16, 0, 0);
        }
    };

    auto compute = [&](int buf) {
#pragma unroll
        for (int kk = 0; kk < 2; ++kk) {
            bf16x8 a[2], b[4];
#pragma unroll
            for (int m = 0; m < 2; ++m) {
                const int rowa = wr * 32 + m * 16 + sub;
                const int c16 = (kk * 4 + g) ^ (rowa & 7);
                a[m] = *(const bf16x8*)((const char*)&As[buf][0] + rowa * 128 + c16 * 16);
            }
#pragma unroll
            for (int n = 0; n < 4; ++n) {
                const int rowb = wc * 64 + n * 16 + sub;
                const int c16 = (kk * 4 + g) ^ (rowb & 7);
                b[n] = *(const bf16x8*)((const char*)&Bs[buf][0] + rowb * 128 + c16 * 16);
            }
#pragma unroll
            for (int m = 0; m < 2; ++m)
#pragma unroll
                for (int n = 0; n < 4; ++n)
                    acc[m][n] = __builtin_amdgcn_mfma_f32_16x16x32_bf16(a[m], b[n], acc[m][n], 0, 0, 0);
        }
    };

    // prologue: tiles 0,1 in flight (per-thread: 6 + 6 = 12 outstanding)
    stage(0, 0);
    stage(1, 1);

    int cb = 0, sb = 2;   // compute buf = kt%3, stage buf = (kt+2)%3 (LDS addr only)
#pragma unroll 1
    for (int kt = 0; kt < NSTEP - 2; ++kt) {
        // outstanding: stage(kt) 6 + stage(kt+1) 6 -> drain exactly stage(kt)
        asm volatile("s_waitcnt vmcnt(6)" ::: "memory");
        __builtin_amdgcn_s_barrier();
        stage(sb, kt + 2);        // buffer freed by compute(kt-1), readers pre-barrier
        __builtin_amdgcn_s_setprio(1);
        compute(cb);
        __builtin_amdgcn_s_setprio(0);
        cb = (cb == 2) ? 0 : cb + 1;
        sb = (sb == 2) ? 0 : sb + 1;
    }
    // kt = 14: outstanding stage(14) 6 + stage(15) 6; drain stage(14)
    asm volatile("s_waitcnt vmcnt(6)" ::: "memory");
    __builtin_amdgcn_s_barrier();
    __builtin_amdgcn_s_setprio(1);
    compute(cb);
    __builtin_amdgcn_s_setprio(0);
    cb = (cb == 2) ? 0 : cb + 1;
    // kt = 15: drain everything
    asm volatile("s_waitcnt vmcnt(0)" ::: "memory");
    __builtin_amdgcn_s_barrier();
    compute(cb);

    // ---- fused epilogue: masked mins over this wave's 64 cols ----
    float psqv[4];
    int   lab[4];
#pragma unroll
    for (int n = 0; n < 4; ++n) {
        const int col = n0 + wc * 64 + n * 16 + sub;
        psqv[n] = psq[col];
        lab[n]  = col >> 2;   // prototype label = col / PPC
    }
    const int part = nb * 2 + wc;
#pragma unroll
    for (int m = 0; m < 2; ++m) {
#pragma unroll
        for (int r = 0; r < 4; ++r) {
            const int rl = wr * 32 + m * 16 + g * 4 + r;
            const float xs = xsq[m0 + rl];
            const int yy = y[m0 + rl];
            float d1 = BIGF, d2 = BIGF;
#pragma unroll
            for (int n = 0; n < 4; ++n) {
                const float dist = xs + psqv[n] - 2.0f * acc[m][n][r];
                if (lab[n] == yy) d1 = fminf(d1, dist);
                else              d2 = fminf(d2, dist);
            }
            for (int off = 8; off; off >>= 1) {
                d1 = fminf(d1, __shfl_xor(d1, off));
                d2 = fminf(d2, __shfl_xor(d2, off));
            }
            if (sub == 0) {
                d1p[part * NS + m0 + rl] = d1;
                d2p[part * NS + m0 + rl] = d2;
            }
        }
    }
}

__global__ __launch_bounds__(256) void finalize_kernel(
    const float* __restrict__ d1p, const float* __restrict__ d2p,
    const int* __restrict__ tval, float* __restrict__ bsum)
{
    const int row = blockIdx.x * 256 + threadIdx.x;
    float d1 = BIGF, d2 = BIGF;
#pragma unroll
    for (int p = 0; p < NPARTS; ++p) {
        d1 = fminf(d1, d1p[p * NS + row]);
        d2 = fminf(d2, d2p[p * NS + row]);
    }
    const float mu = (d1 - d2) / (d1 + d2 + EPSF);
    const float alpha = logf(1.0f + (float)tval[0]);
    float s = 1.0f / (1.0f + expf(-alpha * mu));
    for (int off = 32; off; off >>= 1) s += __shfl_down(s, off);
    __shared__ float red[4];
    if ((threadIdx.x & 63) == 0) red[threadIdx.x >> 6] = s;
    __syncthreads();
    if (threadIdx.x == 0) bsum[blockIdx.x] = red[0] + red[1] + red[2] + red[3];
}

__global__ void final_sum(const float* __restrict__ bsum, float* __restrict__ out) {
    float s = (threadIdx.x < NS / 256) ? bsum[threadIdx.x] : 0.0f;
    for (int off = 32; off; off >>= 1) s += __shfl_down(s, off);
    if (threadIdx.x == 0) out[0] = s * (1.0f / (float)NS);
}

extern "C" void kernel_launch(void* const* d_in, const int* in_sizes, int n_in,
                              void* d_out, int out_size, void* d_ws, size_t ws_size,
                              hipStream_t stream) {
    const float* x      = (const float*)d_in[0];
    const int*   y      = (const int*)d_in[1];
    const int*   tval   = (const int*)d_in[2];
    const float* protos = (const float*)d_in[3];
    float* out = (float*)d_out;

    char* ws = (char*)d_ws;
    unsigned short* xb = (unsigned short*)(ws);                                // 16 MB
    unsigned short* pb = (unsigned short*)(ws + (size_t)NS * DD * 2);          // 1 MB
    float* xsq  = (float*)(ws + (size_t)(NS + NP) * DD * 2);                   // 32 KB
    float* psq  = (float*)(ws + (size_t)(NS + NP) * DD * 2 + NS * 4);          // 2 KB
    float* d1p  = (float*)(ws + (size_t)(NS + NP) * DD * 2 + (NS + NP) * 4);   // 256 KB
    float* d2p  = d1p + (size_t)NPARTS * NS;                                   // 256 KB
    float* bsum = d2p + (size_t)NPARTS * NS;                                   // 128 B

    prep_kernel<<<NS + NP, 256, 0, stream>>>(x, protos, xb, pb, xsq, psq);
    glvq_gemm<<<(NS / MT) * (NP / NT), 256, 0, stream>>>(xb, pb, xsq, psq, y, d1p, d2p);
    finalize_kernel<<<NS / 256, 256, 0, stream>>>(d1p, d2p, tval, bsum);
    final_sum<<<1, 64, 0, stream>>>(bsum, out);
}

// Round 13
// 37.017 us; speedup vs baseline: 1.5954x; 1.0109x over previous
//
#include <hip/hip_runtime.h>
#include <hip/hip_bf16.h>
#include <math.h>
#include <stdint.h>

#define NS 8192       // samples
#define DD 1024       // feature dim
#define NP 512        // prototypes
#define BK 64         // K-chunk
#define MT 64         // M rows per block
#define NT 64         // N cols per block
#define NSTEP (DD / BK)   // 16
#define NPARTS 16     // 8 N-blocks * 2 wave-col-halves
#define EPSF 1e-9f
#define BIGF 3.0e38f

typedef __attribute__((ext_vector_type(8))) short bf16x8;
typedef __attribute__((ext_vector_type(4))) float f32x4;

__device__ inline unsigned short f32_to_bf16(float f) {
    uint32_t u = __builtin_bit_cast(uint32_t, f);
    uint32_t r = (u + 0x7FFFu + ((u >> 16) & 1u)) >> 16;
    return (unsigned short)r;
}

// x and protos f32 -> bf16 + exact f32 row sums of squares (R2-verified).
__global__ __launch_bounds__(256) void prep_kernel(
    const float* __restrict__ x, const float* __restrict__ protos,
    unsigned short* __restrict__ xb, unsigned short* __restrict__ pb,
    float* __restrict__ xsq, float* __restrict__ psq)
{
    int row = blockIdx.x;
    const float* src;
    unsigned short* dstb;
    float* dsts;
    if (row < NS) {
        src = x + (size_t)row * DD; dstb = xb + (size_t)row * DD; dsts = xsq + row;
    } else {
        int r = row - NS;
        src = protos + (size_t)r * DD; dstb = pb + (size_t)r * DD; dsts = psq + r;
    }
    int t = threadIdx.x;
    float4 v = ((const float4*)src)[t];
    float ss = v.x * v.x + v.y * v.y + v.z * v.z + v.w * v.w;
    ushort4 o;
    o.x = f32_to_bf16(v.x); o.y = f32_to_bf16(v.y);
    o.z = f32_to_bf16(v.z); o.w = f32_to_bf16(v.w);
    ((ushort4*)dstb)[t] = o;
    for (int off = 32; off; off >>= 1) ss += __shfl_down(ss, off);
    __shared__ float red[4];
    if ((t & 63) == 0) red[t >> 6] = ss;
    __syncthreads();
    if (t == 0) dsts[0] = red[0] + red[1] + red[2] + red[3];
}

// MAX-OCCUPANCY GEMM+min: 64x64 tile, BK=64, dbuf = 32 KB LDS -> 5 blocks/CU;
// grid 1024 (4-5 blocks/CU, ~18 waves/CU). Latency hidden by cross-block
// overlap (the R2->R3 proven lever) + counted-drain schedule (R6->R7 lever):
// per iter vmcnt(0) [exact: only stage(kt) outstanding] -> barrier ->
// stage(kt+1) [flies through compute] -> compute(kt). XOR-swizzled LDS.
// XCD-bijective decode: per XCD 16 M-blocks x 8 N-blocks (2MB xb + 1MB pb, L2-fit).
__global__ __launch_bounds__(256, 5) void glvq_gemm(
    const unsigned short* __restrict__ xb, const unsigned short* __restrict__ pb,
    const float* __restrict__ xsq, const float* __restrict__ psq,
    const int* __restrict__ y,
    float* __restrict__ d1p, float* __restrict__ d2p)
{
    __shared__ unsigned short As[2][MT * BK];   // 2 x 8 KB
    __shared__ unsigned short Bs[2][NT * BK];   // 2 x 8 KB

    const int tid  = threadIdx.x;
    const int lane = tid & 63;
    const int wid  = tid >> 6;        // 0..3
    const int wr = wid >> 1;          // 0..1 -> rows wr*32
    const int wc = wid & 1;           // 0..1 -> cols wc*32
    const int d    = blockIdx.x;      // 0..1023
    const int xcd  = d & 7;
    const int slot = d >> 3;          // 0..127
    const int mb   = xcd * 16 + (slot & 15);   // 0..127
    const int nb   = slot >> 4;                // 0..7
    const int m0   = mb * MT;
    const int n0   = nb * NT;

    const int srow   = lane >> 3;                 // 0..7
    const int scol16 = (lane & 7) ^ srow;         // pre-swizzled source chunk
    const int sub = lane & 15, g = lane >> 4;

    f32x4 acc[2][2] = {};

    // stage tile kt: A 8 chunks (1 KB, 8 rows each), B 8 chunks; wave w covers
    // chunks {2w,2w+1} of each. 4 gll insts/thread. Linear LDS dest, swizzled src.
    auto stage = [&](int buf, int kt) {
        const int k0 = kt * BK;
#pragma unroll
        for (int j = 0; j < 2; ++j) {
            const int c = wid * 2 + j;
            const unsigned short* ga = xb + (size_t)(m0 + c * 8 + srow) * DD + k0 + scol16 * 8;
            __builtin_amdgcn_global_load_lds(
                (const __attribute__((address_space(1))) void*)ga,
                (__attribute__((address_space(3))) void*)((char*)&As[buf][0] + c * 1024),
                16, 0, 0);
        }
#pragma unroll
        for (int j = 0; j < 2; ++j) {
            const int c = wid * 2 + j;
            const unsigned short* gb = pb + (size_t)(n0 + c * 8 + srow) * DD + k0 + scol16 * 8;
            __builtin_amdgcn_global_load_lds(
                (const __attribute__((address_space(1))) void*)gb,
                (__attribute__((address_space(3))) void*)((char*)&Bs[buf][0] + c * 1024),
                16, 0, 0);
        }
    };

    auto compute = [&](int buf) {
#pragma unroll
        for (int kk = 0; kk < 2; ++kk) {
            bf16x8 a[2], b[2];
#pragma unroll
            for (int m = 0; m < 2; ++m) {
                const int rowa = wr * 32 + m * 16 + sub;
                const int c16 = (kk * 4 + g) ^ (rowa & 7);
                a[m] = *(const bf16x8*)((const char*)&As[buf][0] + rowa * 128 + c16 * 16);
            }
#pragma unroll
            for (int n = 0; n < 2; ++n) {
                const int rowb = wc * 32 + n * 16 + sub;
                const int c16 = (kk * 4 + g) ^ (rowb & 7);
                b[n] = *(const bf16x8*)((const char*)&Bs[buf][0] + rowb * 128 + c16 * 16);
            }
#pragma unroll
            for (int m = 0; m < 2; ++m)
#pragma unroll
                for (int n = 0; n < 2; ++n)
                    acc[m][n] = __builtin_amdgcn_mfma_f32_16x16x32_bf16(a[m], b[n], acc[m][n], 0, 0, 0);
        }
    };

    stage(0, 0);
    int buf = 0;
#pragma unroll 1
    for (int kt = 0; kt < NSTEP - 1; ++kt) {
        // only stage(kt)'s 4 loads outstanding -> exact drain
        asm volatile("s_waitcnt vmcnt(0)" ::: "memory");
        __builtin_amdgcn_s_barrier();
        stage(buf ^ 1, kt + 1);   // prefetch flies through compute(kt)
        __builtin_amdgcn_s_setprio(1);
        compute(buf);
        __builtin_amdgcn_s_setprio(0);
        buf ^= 1;
    }
    asm volatile("s_waitcnt vmcnt(0)" ::: "memory");
    __builtin_amdgcn_s_barrier();
    compute(buf);

    // ---- fused epilogue: masked mins over this wave's 32 cols ----
    float psqv[2];
    int   lab[2];
#pragma unroll
    for (int n = 0; n < 2; ++n) {
        const int col = n0 + wc * 32 + n * 16 + sub;
        psqv[n] = psq[col];
        lab[n]  = col >> 2;   // prototype label = col / PPC
    }
    const int part = nb * 2 + wc;
#pragma unroll
    for (int m = 0; m < 2; ++m) {
#pragma unroll
        for (int r = 0; r < 4; ++r) {
            const int rl = wr * 32 + m * 16 + g * 4 + r;
            const float xs = xsq[m0 + rl];
            const int yy = y[m0 + rl];
            float d1 = BIGF, d2 = BIGF;
#pragma unroll
            for (int n = 0; n < 2; ++n) {
                const float dist = xs + psqv[n] - 2.0f * acc[m][n][r];
                if (lab[n] == yy) d1 = fminf(d1, dist);
                else              d2 = fminf(d2, dist);
            }
            for (int off = 8; off; off >>= 1) {
                d1 = fminf(d1, __shfl_xor(d1, off));
                d2 = fminf(d2, __shfl_xor(d2, off));
            }
            if (sub == 0) {
                d1p[part * NS + m0 + rl] = d1;
                d2p[part * NS + m0 + rl] = d2;
            }
        }
    }
}

__global__ __launch_bounds__(256) void finalize_kernel(
    const float* __restrict__ d1p, const float* __restrict__ d2p,
    const int* __restrict__ tval, float* __restrict__ bsum)
{
    const int row = blockIdx.x * 256 + threadIdx.x;
    float d1 = BIGF, d2 = BIGF;
#pragma unroll
    for (int p = 0; p < NPARTS; ++p) {
        d1 = fminf(d1, d1p[p * NS + row]);
        d2 = fminf(d2, d2p[p * NS + row]);
    }
    const float mu = (d1 - d2) / (d1 + d2 + EPSF);
    const float alpha = logf(1.0f + (float)tval[0]);
    float s = 1.0f / (1.0f + expf(-alpha * mu));
    for (int off = 32; off; off >>= 1) s += __shfl_down(s, off);
    __shared__ float red[4];
    if ((threadIdx.x & 63) == 0) red[threadIdx.x >> 6] = s;
    __syncthreads();
    if (threadIdx.x == 0) bsum[blockIdx.x] = red[0] + red[1] + red[2] + red[3];
}

__global__ void final_sum(const float* __restrict__ bsum, float* __restrict__ out) {
    float s = (threadIdx.x < NS / 256) ? bsum[threadIdx.x] : 0.0f;
    for (int off = 32; off; off >>= 1) s += __shfl_down(s, off);
    if (threadIdx.x == 0) out[0] = s * (1.0f / (float)NS);
}

extern "C" void kernel_launch(void* const* d_in, const int* in_sizes, int n_in,
                              void* d_out, int out_size, void* d_ws, size_t ws_size,
                              hipStream_t stream) {
    const float* x      = (const float*)d_in[0];
    const int*   y      = (const int*)d_in[1];
    const int*   tval   = (const int*)d_in[2];
    const float* protos = (const float*)d_in[3];
    float* out = (float*)d_out;

    char* ws = (char*)d_ws;
    unsigned short* xb = (unsigned short*)(ws);                                // 16 MB
    unsigned short* pb = (unsigned short*)(ws + (size_t)NS * DD * 2);          // 1 MB
    float* xsq  = (float*)(ws + (size_t)(NS + NP) * DD * 2);                   // 32 KB
    float* psq  = (float*)(ws + (size_t)(NS + NP) * DD * 2 + NS * 4);          // 2 KB
    float* d1p  = (float*)(ws + (size_t)(NS + NP) * DD * 2 + (NS + NP) * 4);   // 512 KB
    float* d2p  = d1p + (size_t)NPARTS * NS;                                   // 512 KB
    float* bsum = d2p + (size_t)NPARTS * NS;                                   // 128 B

    prep_kernel<<<NS + NP, 256, 0, stream>>>(x, protos, xb, pb, xsq, psq);
    glvq_gemm<<<(NS / MT) * (NP / NT), 256, 0, stream>>>(xb, pb, xsq, psq, y, d1p, d2p);
    finalize_kernel<<<NS / 256, 256, 0, stream>>>(d1p, d2p, tval, bsum);
    final_sum<<<1, 64, 0, stream>>>(bsum, out);
}